// Round 7
// baseline (421.504 us; speedup 1.0000x reference)
//
#include <hip/hip_runtime.h>
#include <hip/hip_bf16.h>

typedef __hip_bfloat16 bf16;
typedef unsigned short ushort_t;
typedef __attribute__((ext_vector_type(8))) short short8;
typedef __attribute__((ext_vector_type(4))) float f32x4;

#define NN 100000   // nodes
#define NE 640000   // edges
#define HD 128      // hidden
#define NB ((NN + 255) / 256)   // 391 scan blocks

// flags[a]: 1 if float-array a is stored as f32, 0 if bf16 (input dtype sniffing).
// a: 0=node_emb 1=type_emb 2=len_emb 3=lane_emb 4=W(+b) 5=adj_val
// Internal X/SUP are ALWAYS bf16; flags only pick input load width + d_out dtype.
__device__ __forceinline__ float ldmix(const void* p, size_t i, int f32) {
    return f32 ? ((const float*)p)[i]
               : __bfloat162float(((const bf16*)p)[i]);
}
__device__ __forceinline__ int allf32(const int* flags) {
    return flags[0] & flags[1] & flags[2] & flags[3] & flags[4] & flags[5];
}
__device__ __forceinline__ float bf2f(ushort_t u) {
    unsigned v = (unsigned)u << 16;
    return __builtin_bit_cast(float, v);
}
__device__ __forceinline__ ushort_t f2bf(float f) {
    bf16 h = __float2bfloat16(f);
    return *(ushort_t*)&h;
}

// Per-array dtype sniffing: real bf16 data here has |v| < 1 (exp <= 126).
// f32 bits misread as bf16 halves have exponent >= 130 with p ~ 0.5/word.
__global__ __launch_bounds__(256) void detect_kernel(
        const void* node_emb, const void* type_emb, const void* len_emb,
        const void* lane_emb, const void* W, const void* adj_val,
        int* __restrict__ flags) {
    __shared__ int found;
    const int a = blockIdx.x;  // 0..5
    const unsigned short* p;
    int n;
    switch (a) {
        case 0: p = (const unsigned short*)node_emb; n = 100000 * 64; break;
        case 1: p = (const unsigned short*)type_emb; n = 20 * 32;     break;
        case 2: p = (const unsigned short*)len_emb;  n = 100 * 16;    break;
        case 3: p = (const unsigned short*)lane_emb; n = 10 * 16;     break;
        case 4: p = (const unsigned short*)W;        n = HD * HD;     break;
        default: p = (const unsigned short*)adj_val; n = NE;          break;
    }
    if (n > 16384) n = 16384;
    if (threadIdx.x == 0) found = 0;
    __syncthreads();
    int loc = 0;
    for (int i = threadIdx.x; i < n; i += 256) {
        int e = (p[i] >> 7) & 0xFF;
        if (e >= 130) loc = 1;
    }
    if (loc) atomicOr(&found, 1);
    __syncthreads();
    if (threadIdx.x == 0) flags[a] = found;
}

// X[i,:] = concat(lane[16], type[32], length[16], node[64]) -> bf16.
// 8 cols per thread: boundaries (16,48,64) are multiples of 8.
__global__ __launch_bounds__(256) void embed_kernel(const int* __restrict__ nodef,
        const int* __restrict__ typef, const int* __restrict__ lenf,
        const int* __restrict__ lanef,
        const void* __restrict__ node_emb, const void* __restrict__ type_emb,
        const void* __restrict__ len_emb, const void* __restrict__ lane_emb,
        const int* __restrict__ flags, ushort_t* __restrict__ X) {
    int idx = blockIdx.x * 256 + threadIdx.x;   // grid exactly NN*16
    int i = idx >> 4;
    int c = (idx & 15) * 8;
    const void* tbl;
    size_t base;
    int f;
    if (c < 16)      { tbl = lane_emb; base = (size_t)lanef[i] * 16 + c;        f = flags[3]; }
    else if (c < 48) { tbl = type_emb; base = (size_t)typef[i] * 32 + (c - 16); f = flags[1]; }
    else if (c < 64) { tbl = len_emb;  base = (size_t)lenf[i]  * 16 + (c - 48); f = flags[2]; }
    else             { tbl = node_emb; base = (size_t)nodef[i] * 64 + (c - 64); f = flags[0]; }
    ushort_t u[8];
#pragma unroll
    for (int j = 0; j < 8; ++j) u[j] = f2bf(ldmix(tbl, base + j, f));
    *(uint4*)(X + (size_t)i * HD + c) = *(uint4*)u;
}

// ---- CSR build ----

__global__ __launch_bounds__(256) void hist_kernel(const int* __restrict__ dst,
                                                   int* __restrict__ cnt) {
    int e = blockIdx.x * 256 + threadIdx.x;   // grid exactly NE
    atomicAdd(&cnt[dst[e]], 1);
}

__global__ __launch_bounds__(256) void scan1_kernel(const int* __restrict__ cnt,
                                                    int* __restrict__ bsum) {
    int idx = blockIdx.x * 256 + threadIdx.x;
    int v = (idx < NN) ? cnt[idx] : 0;
    for (int o = 32; o; o >>= 1) v += __shfl_down(v, o, 64);
    __shared__ int ws_[4];
    if ((threadIdx.x & 63) == 0) ws_[threadIdx.x >> 6] = v;
    __syncthreads();
    if (threadIdx.x == 0) bsum[blockIdx.x] = ws_[0] + ws_[1] + ws_[2] + ws_[3];
}

// fused: per-block prefix over bsum (L2-resident, <=390 ints) + local scan
__global__ __launch_bounds__(256) void scan3_kernel(const int* __restrict__ cnt,
        const int* __restrict__ bsum, int* __restrict__ offs, int* __restrict__ pos) {
    __shared__ int s[256];
    __shared__ int bofs;
    const int b = blockIdx.x;
    const int t = threadIdx.x;
    // block offset = sum(bsum[0..b-1])
    int acc = 0;
    for (int i = t; i < b; i += 256) acc += bsum[i];
    s[t] = acc;
    __syncthreads();
    for (int o = 128; o; o >>= 1) {
        if (t < o) s[t] += s[t + o];
        __syncthreads();
    }
    if (t == 0) bofs = s[0];
    __syncthreads();
    const int boffv = bofs;
    __syncthreads();   // s[] reuse below
    // local exclusive scan of this block's 256 counts
    int idx = b * 256 + t;
    int v = (idx < NN) ? cnt[idx] : 0;
    s[t] = v;
    __syncthreads();
    for (int o = 1; o < 256; o <<= 1) {
        int u = (t >= o) ? s[t - o] : 0;
        __syncthreads();
        s[t] += u;
        __syncthreads();
    }
    int excl = s[t] - v + boffv;
    if (idx <= NN) {
        offs[idx] = excl;
        if (idx < NN) pos[idx] = excl;
    }
}

__global__ __launch_bounds__(256) void position_kernel(const int* __restrict__ src,
        const int* __restrict__ dst, const void* __restrict__ val,
        const int* __restrict__ flags, int* __restrict__ pos,
        int* __restrict__ esrc, float* __restrict__ eval) {
    int e = blockIdx.x * 256 + threadIdx.x;   // grid exactly NE
    int d = dst[e];
    int slot = atomicAdd(&pos[d], 1);
    esrc[slot] = src[e];
    eval[slot] = ldmix(val, e, flags[5]);
}

// W -> Wt[n][k] bf16 (pre-transposed so MFMA B-frags are 16B-contiguous)
__global__ __launch_bounds__(256) void prep_kernel(const void* __restrict__ W,
        const int* __restrict__ flags, ushort_t* __restrict__ Wt) {
    int idx = blockIdx.x * 256 + threadIdx.x;   // grid 64 -> 16384
    int n = idx >> 7;
    int k = idx & 127;
    Wt[idx] = f2bf(ldmix(W, (size_t)k * HD + n, flags[4]));
}

// ---- per-layer kernels ----

// SUP = X @ W via mfma_f32_16x16x32_bf16 — LDS-free, barrier-free.
// 256 thr = 4 waves, 128 rows/block; wave w owns cols [w*32, w*32+32).
// B-frags (W^T, 32 KB, L2-resident) loaded once into registers; A-frags
// loaded 16B-contiguous from row-major bf16 X per 16-row tile.
// A[m=lane&15][k=quad*8+j]; B[k][n=lane&15]; C/D: col=lane&15, row=quad*4+reg.
__global__ __launch_bounds__(256) void gemm_kernel(const ushort_t* __restrict__ X,
        const ushort_t* __restrict__ Wt, ushort_t* __restrict__ sup) {
    const int tid = threadIdx.x;
    const int row0 = blockIdx.x * 128;
    const int w = tid >> 6;
    const int lane = tid & 63;
    const int ln = lane & 15;
    const int quad = lane >> 4;
    const int koff = quad * 8;

    short8 bfrg[2][4];
#pragma unroll
    for (int nt = 0; nt < 2; ++nt)
#pragma unroll
        for (int kc = 0; kc < 4; ++kc)
            bfrg[nt][kc] = *(const short8*)&Wt[(size_t)(w * 32 + nt * 16 + ln) * HD + kc * 32 + koff];

    const f32x4 zero = {0.f, 0.f, 0.f, 0.f};
#pragma unroll
    for (int mt = 0; mt < 8; ++mt) {
        int gmA = row0 + mt * 16 + ln;
        if (gmA >= NN) gmA = NN - 1;
        short8 afrg[4];
#pragma unroll
        for (int kc = 0; kc < 4; ++kc)
            afrg[kc] = *(const short8*)&X[(size_t)gmA * HD + kc * 32 + koff];
        f32x4 acc[2] = {zero, zero};
#pragma unroll
        for (int nt = 0; nt < 2; ++nt)
#pragma unroll
            for (int kc = 0; kc < 4; ++kc)
                acc[nt] = __builtin_amdgcn_mfma_f32_16x16x32_bf16(
                        afrg[kc], bfrg[nt][kc], acc[nt], 0, 0, 0);
#pragma unroll
        for (int reg = 0; reg < 4; ++reg) {
            int gm = row0 + mt * 16 + quad * 4 + reg;
            if (gm < NN) {
#pragma unroll
                for (int nt = 0; nt < 2; ++nt)
                    sup[(size_t)gm * HD + w * 32 + nt * 16 + ln] = f2bf(acc[nt][reg]);
            }
        }
    }
}

// Pull-mode aggregation: one wave per dst node, f32 accumulate, bf16 X store.
// X[d,:] = b + sum_j eval[j] * SUP[esrc[j],:]; final layer also writes d_out.
__global__ __launch_bounds__(256) void agg_kernel(const ushort_t* __restrict__ sup,
        const int* __restrict__ offs, const int* __restrict__ esrc,
        const float* __restrict__ eval, const void* __restrict__ b_,
        const int* __restrict__ flags, ushort_t* __restrict__ X,
        void* __restrict__ out, int write_out) {
    const int node = __builtin_amdgcn_readfirstlane(
            blockIdx.x * 4 + (threadIdx.x >> 6));   // grid exactly NN/4
    const int lane = threadIdx.x & 63;
    const int c = lane * 2;
    const int lo = offs[node];
    const int hi = offs[node + 1];
    float2 a0 = {0.f, 0.f}, a1 = {0.f, 0.f}, a2 = {0.f, 0.f}, a3 = {0.f, 0.f};
    int j = lo;
    for (; j + 3 < hi; j += 4) {   // 4 accumulators -> 4 outstanding gathers
        const int s0 = esrc[j], s1 = esrc[j + 1], s2 = esrc[j + 2], s3 = esrc[j + 3];
        const float v0 = eval[j], v1 = eval[j + 1], v2 = eval[j + 2], v3 = eval[j + 3];
        const ushort2 u0 = *(const ushort2*)(sup + (size_t)s0 * HD + c);
        const ushort2 u1 = *(const ushort2*)(sup + (size_t)s1 * HD + c);
        const ushort2 u2 = *(const ushort2*)(sup + (size_t)s2 * HD + c);
        const ushort2 u3 = *(const ushort2*)(sup + (size_t)s3 * HD + c);
        a0.x += bf2f(u0.x) * v0;  a0.y += bf2f(u0.y) * v0;
        a1.x += bf2f(u1.x) * v1;  a1.y += bf2f(u1.y) * v1;
        a2.x += bf2f(u2.x) * v2;  a2.y += bf2f(u2.y) * v2;
        a3.x += bf2f(u3.x) * v3;  a3.y += bf2f(u3.y) * v3;
    }
    for (; j < hi; ++j) {
        const int s0 = esrc[j];
        const float v0 = eval[j];
        const ushort2 u0 = *(const ushort2*)(sup + (size_t)s0 * HD + c);
        a0.x += bf2f(u0.x) * v0;  a0.y += bf2f(u0.y) * v0;
    }
    float2 acc;
    acc.x = (a0.x + a1.x) + (a2.x + a3.x) + ldmix(b_, c, flags[4]);
    acc.y = (a0.y + a1.y) + (a2.y + a3.y) + ldmix(b_, c + 1, flags[4]);
    const size_t o = (size_t)node * HD + c;
    ushort2 u; u.x = f2bf(acc.x); u.y = f2bf(acc.y);
    *(ushort2*)(X + o) = u;
    if (write_out) {
        if (allf32(flags)) { float2 f; f.x = acc.x; f.y = acc.y;
                             *(float2*)((float*)out + o) = f; }
        else               { *(ushort2*)((ushort_t*)out + o) = u; }
    }
}

// fallback tier only (SUP aliased to d_out): final X -> out copy/convert
__global__ __launch_bounds__(256) void cast_kernel(const ushort_t* __restrict__ X,
        const int* __restrict__ flags, void* __restrict__ out) {
    int idx = blockIdx.x * 256 + threadIdx.x;   // grid exactly NN*HD
    ushort_t u = X[idx];
    if (allf32(flags)) ((float*)out)[idx] = bf2f(u);
    else               ((ushort_t*)out)[idx] = u;
}

extern "C" void kernel_launch(void* const* d_in, const int* in_sizes, int n_in,
                              void* d_out, int out_size, void* d_ws, size_t ws_size,
                              hipStream_t stream) {
    const int*  nodef    = (const int*)d_in[0];
    const int*  typef    = (const int*)d_in[1];
    const int*  lenf     = (const int*)d_in[2];
    const int*  lanef    = (const int*)d_in[3];
    const int*  adj_src  = (const int*)d_in[4];
    const int*  adj_dst  = (const int*)d_in[5];
    const void* adj_val  = d_in[6];
    const void* node_emb = d_in[7];
    const void* type_emb = d_in[8];
    const void* len_emb  = d_in[9];
    const void* lane_emb = d_in[10];
    const void* W        = d_in[11];
    const void* b        = d_in[12];

    // ws layout (chunks 16B-aligned); X/SUP internal bf16 always
    const size_t xbytes = (size_t)NN * HD * 2;   // 25.6 MB
    char* wp = (char*)d_ws;
    int*      flags = (int*)wp;      wp += 256;
    ushort_t* X     = (ushort_t*)wp; wp += xbytes;
    int*      cnt   = (int*)wp;      wp += (size_t)NN * 4;
    int*      offs  = (int*)wp;      wp += 400016;            // NN+1 ints, padded
    int*      pos   = (int*)wp;      wp += (size_t)NN * 4;
    int*      esrc  = (int*)wp;      wp += (size_t)NE * 4;
    float*    eval  = (float*)wp;    wp += (size_t)NE * 4;
    ushort_t* Wt    = (ushort_t*)wp; wp += 32768;
    int*      bsum  = (int*)wp;      wp += 1600;
    const size_t used = (size_t)(wp - (char*)d_ws);

    ushort_t* SUP;
    int sup_is_out;
    if (ws_size >= used + xbytes) { SUP = (ushort_t*)wp;    sup_is_out = 0; }
    else                          { SUP = (ushort_t*)d_out; sup_is_out = 1; }

    detect_kernel<<<6, 256, 0, stream>>>(node_emb, type_emb, len_emb, lane_emb,
                                         W, adj_val, flags);
    embed_kernel<<<(NN * 16) / 256, 256, 0, stream>>>(nodef, typef, lenf, lanef,
            node_emb, type_emb, len_emb, lane_emb, flags, X);

    // CSR build (graph identical across layers)
    hipMemsetAsync(cnt, 0, (size_t)NN * 4, stream);
    hist_kernel<<<NE / 256, 256, 0, stream>>>(adj_dst, cnt);
    scan1_kernel<<<NB, 256, 0, stream>>>(cnt, bsum);
    scan3_kernel<<<NB, 256, 0, stream>>>(cnt, bsum, offs, pos);
    position_kernel<<<NE / 256, 256, 0, stream>>>(adj_src, adj_dst, adj_val,
                                                  flags, pos, esrc, eval);
    prep_kernel<<<64, 256, 0, stream>>>(W, flags, Wt);

    for (int l = 0; l < 3; ++l) {
        gemm_kernel<<<(NN + 127) / 128, 256, 0, stream>>>(X, Wt, SUP);
        const int wout = (l == 2 && !sup_is_out) ? 1 : 0;
        agg_kernel<<<NN / 4, 256, 0, stream>>>(SUP, offs, esrc, eval,
                                               b, flags, X, d_out, wout);
    }
    if (sup_is_out)
        cast_kernel<<<(NN * HD) / 256, 256, 0, stream>>>(X, flags, d_out);
}